// Round 3
// baseline (170.158 us; speedup 1.0000x reference)
//
#include <hip/hip_runtime.h>

constexpr int NRAYS = 131072;
constexpr float DELTA_INF_F = 1e10f;
constexpr float EPS_F = 1e-10f;
constexpr int GRID  = 2048;
constexpr int BLOCK = 256;
constexpr int WAVES = GRID * (BLOCK / 64);   // 8192 waves
constexpr int ITERS = NRAYS / WAVES;         // 16 rays per wave

// 48 active lanes per wave; lane l owns samples 4l..4l+3 of its ray.
// No LDS, no barriers: weights are lane-local by construction.
__global__ __launch_bounds__(256) void nerf_render_kernel(
    const float4* __restrict__ rsF4,    // [N*144] positions
    const float4* __restrict__ denF4,   // [N*48]  densities
    const float4* __restrict__ rgbF4,   // [N*144] rgb
    const float* __restrict__ bg,       // [3]
    float* __restrict__ out_rgb,        // [N,3]
    float* __restrict__ out_acc,        // [N]
    float4* __restrict__ out_wF4)       // [N*48]
{
    const int lane = threadIdx.x & 63;
    const int gw   = (int)((blockIdx.x * BLOCK + threadIdx.x) >> 6);
    const bool act = lane < 48;
    const float bg0 = bg[0], bg1 = bg[1], bg2 = bg[2];
    const float4 Z = make_float4(0.f, 0.f, 0.f, 0.f);

    int ray = gw;
    float4 P0 = Z, P1 = Z, P2 = Z, D = Z, C0 = Z, C1 = Z, C2 = Z;
    if (act) {
        const float4* rp = rsF4 + (size_t)ray * 144 + 3 * lane;
        P0 = rp[0]; P1 = rp[1]; P2 = rp[2];
        D = denF4[(size_t)ray * 48 + lane];
        const float4* rc = rgbF4 + (size_t)ray * 144 + 3 * lane;
        C0 = rc[0]; C1 = rc[1]; C2 = rc[2];
    }

#pragma unroll 2
    for (int it = 0; it < ITERS; ++it) {
        // ---- prefetch next ray's data (issued before current compute) ----
        int nray = ray + WAVES;
        float4 nP0 = Z, nP1 = Z, nP2 = Z, nD = Z, nC0 = Z, nC1 = Z, nC2 = Z;
        if (act && (it + 1 < ITERS)) {
            const float4* rp = rsF4 + (size_t)nray * 144 + 3 * lane;
            nP0 = rp[0]; nP1 = rp[1]; nP2 = rp[2];
            nD = denF4[(size_t)nray * 48 + lane];
            const float4* rc = rgbF4 + (size_t)nray * 144 + 3 * lane;
            nC0 = rc[0]; nC1 = rc[1]; nC2 = rc[2];
        }

        // ---- unpack 4 samples (compile-time components) ----
        float x0 = P0.x, y0 = P0.y, z0 = P0.z;
        float x1 = P0.w, y1 = P1.x, z1 = P1.y;
        float x2 = P1.z, y2 = P1.w, z2 = P2.x;
        float x3 = P2.y, y3 = P2.z, z3 = P2.w;

        float nx = __shfl_down(x0, 1);
        float ny = __shfl_down(y0, 1);
        float nz = __shfl_down(z0, 1);

        float dx = x1 - x0, dy = y1 - y0, dz = z1 - z0;
        float d0 = sqrtf(dx * dx + dy * dy + dz * dz);
        dx = x2 - x1; dy = y2 - y1; dz = z2 - z1;
        float d1 = sqrtf(dx * dx + dy * dy + dz * dz);
        dx = x3 - x2; dy = y3 - y2; dz = z3 - z2;
        float d2 = sqrtf(dx * dx + dy * dy + dz * dz);
        dx = nx - x3; dy = ny - y3; dz = nz - z3;
        float d3 = (lane == 47) ? DELTA_INF_F : sqrtf(dx * dx + dy * dy + dz * dz);

        // ---- alpha / transmittance factors (mirror reference algebra) ----
        float e0 = __expf(-fmaxf(D.x, 0.f) * d0);
        float e1 = __expf(-fmaxf(D.y, 0.f) * d1);
        float e2 = __expf(-fmaxf(D.z, 0.f) * d2);
        float e3 = __expf(-fmaxf(D.w, 0.f) * d3);
        float a0 = 1.f - e0, a1 = 1.f - e1, a2 = 1.f - e2, a3 = 1.f - e3;
        float t0 = (1.f - a0) + EPS_F;
        float t1 = (1.f - a1) + EPS_F;
        float t2 = (1.f - a2) + EPS_F;
        float t3 = (1.f - a3) + EPS_F;

        // ---- exclusive cumprod across lanes (6-step scan) ----
        float t01 = t0 * t1;
        float t012 = t01 * t2;
        float incl = t012 * t3;
#pragma unroll
        for (int off = 1; off < 64; off <<= 1) {
            float t = __shfl_up(incl, off);
            if (lane >= off) incl *= t;
        }
        float pref = __shfl_up(incl, 1);
        if (lane == 0) pref = 1.f;

        float w0 = a0 * pref;
        float w1 = a1 * pref * t0;
        float w2 = a2 * pref * t01;
        float w3 = a3 * pref * t012;
        float acc = w0 + w1 + w2 + w3;

        // ---- coalesced weight store (one float4 per lane) ----
        if (act)
            out_wF4[(size_t)ray * 48 + lane] = make_float4(w0, w1, w2, w3);

        // ---- weighted rgb, all lane-local ----
        float cr = w0 * C0.x + w1 * C0.w + w2 * C1.z + w3 * C2.y;
        float cg = w0 * C0.y + w1 * C1.x + w2 * C1.w + w3 * C2.z;
        float cb = w0 * C0.z + w1 * C1.y + w2 * C2.x + w3 * C2.w;

#pragma unroll
        for (int off = 32; off >= 1; off >>= 1) {
            cr  += __shfl_xor(cr, off);
            cg  += __shfl_xor(cg, off);
            cb  += __shfl_xor(cb, off);
            acc += __shfl_xor(acc, off);
        }

        if (lane == 0) {
            float om = 1.f - acc;
            out_rgb[(size_t)ray * 3 + 0] = cr + bg0 * om;
            out_rgb[(size_t)ray * 3 + 1] = cg + bg1 * om;
            out_rgb[(size_t)ray * 3 + 2] = cb + bg2 * om;
            out_acc[ray] = acc;
        }

        // ---- rotate prefetched registers in ----
        P0 = nP0; P1 = nP1; P2 = nP2; D = nD; C0 = nC0; C1 = nC1; C2 = nC2;
        ray = nray;
    }
}

extern "C" void kernel_launch(void* const* d_in, const int* in_sizes, int n_in,
                              void* d_out, int out_size, void* d_ws, size_t ws_size,
                              hipStream_t stream) {
    const float4* rsF4  = (const float4*)d_in[0];
    const float4* denF4 = (const float4*)d_in[1];
    const float4* rgbF4 = (const float4*)d_in[2];
    const float*  bg    = (const float*)d_in[3];

    float* o = (float*)d_out;
    float*  out_rgb = o;                                  // N*3
    float*  out_acc = o + (size_t)NRAYS * 3;              // N
    float4* out_wF4 = (float4*)(o + (size_t)NRAYS * 4);   // N*192

    dim3 grid(GRID), block(BLOCK);
    hipLaunchKernelGGL(nerf_render_kernel, grid, block, 0, stream,
                       rsF4, denF4, rgbF4, bg, out_rgb, out_acc, out_wF4);
}

// Round 4
// 149.233 us; speedup vs baseline: 1.1402x; 1.1402x over previous
//
#include <hip/hip_runtime.h>

constexpr int NRAYS = 131072;
constexpr int S = 192;
constexpr float DELTA_INF_F = 1e10f;
constexpr float EPS_F = 1e-10f;

// One 64-lane wave per ray; lane l owns samples [3l, 3l+2]. 4 rays/block.
// R1 structure + nontemporal output stores + __expf.
__global__ __launch_bounds__(256) void nerf_render_kernel(
    const float* __restrict__ ray_samples,  // [N,S,3]
    const float* __restrict__ densities,    // [N,S]
    const float* __restrict__ rgb,          // [N,S,3]
    const float* __restrict__ bg,           // [3]
    float* __restrict__ out_rgb,            // [N,3]
    float* __restrict__ out_acc,            // [N]
    float* __restrict__ out_w)              // [N,S]
{
    const int lane = threadIdx.x & 63;
    const int ray  = (blockIdx.x << 2) + (threadIdx.x >> 6);

    const size_t rbase = (size_t)ray * S;

    // ---- positions: 9 contiguous floats per lane (3 samples x xyz) ----
    const float* rs = ray_samples + rbase * 3 + lane * 9;
    float p[9];
#pragma unroll
    for (int j = 0; j < 9; ++j) p[j] = rs[j];

    // next sample's xyz comes from lane+1's first sample
    float xn = __shfl_down(p[0], 1);
    float yn = __shfl_down(p[1], 1);
    float zn = __shfl_down(p[2], 1);

    float dx = p[3] - p[0], dy = p[4] - p[1], dz = p[5] - p[2];
    float d0 = sqrtf(dx*dx + dy*dy + dz*dz);
    dx = p[6] - p[3]; dy = p[7] - p[4]; dz = p[8] - p[5];
    float d1 = sqrtf(dx*dx + dy*dy + dz*dz);
    float d2 = DELTA_INF_F;                 // last sample of the ray
    if (lane < 63) {
        dx = xn - p[6]; dy = yn - p[7]; dz = zn - p[8];
        d2 = sqrtf(dx*dx + dy*dy + dz*dz);
    }

    // ---- densities: 3 contiguous floats per lane ----
    const float* dn = densities + rbase + lane * 3;
    float e0 = __expf(-fmaxf(dn[0], 0.0f) * d0);
    float e1 = __expf(-fmaxf(dn[1], 0.0f) * d1);
    float e2 = __expf(-fmaxf(dn[2], 0.0f) * d2);

    // mirror reference algebra: alpha = 1-e ; t = (1-alpha) + eps
    float a0 = 1.0f - e0, a1 = 1.0f - e1, a2 = 1.0f - e2;
    float t0 = (1.0f - a0) + EPS_F;
    float t1 = (1.0f - a1) + EPS_F;
    float t2 = (1.0f - a2) + EPS_F;

    // ---- exclusive cumprod across the ray ----
    float incl = t0 * t1 * t2;           // this lane's total product
#pragma unroll
    for (int off = 1; off < 64; off <<= 1) {
        float t = __shfl_up(incl, off);
        if (lane >= off) incl *= t;
    }
    float pref = __shfl_up(incl, 1);     // exclusive prefix across lanes
    if (lane == 0) pref = 1.0f;

    float w0 = a0 * pref;
    float w1 = a1 * pref * t0;
    float w2 = a2 * pref * t0 * t1;

    // ---- write weights (nontemporal: pure streaming output) ----
    float* wout = out_w + rbase + lane * 3;
    __builtin_nontemporal_store(w0, wout + 0);
    __builtin_nontemporal_store(w1, wout + 1);
    __builtin_nontemporal_store(w2, wout + 2);

    // ---- weighted rgb + alpha sums ----
    const float* cg = rgb + rbase * 3 + lane * 9;
    float cr = w0*cg[0] + w1*cg[3] + w2*cg[6];
    float cgrn = w0*cg[1] + w1*cg[4] + w2*cg[7];
    float cb = w0*cg[2] + w1*cg[5] + w2*cg[8];
    float acc = w0 + w1 + w2;

#pragma unroll
    for (int off = 32; off >= 1; off >>= 1) {
        cr   += __shfl_xor(cr, off);
        cgrn += __shfl_xor(cgrn, off);
        cb   += __shfl_xor(cb, off);
        acc  += __shfl_xor(acc, off);
    }

    if (lane == 0) {
        float om = 1.0f - acc;
        __builtin_nontemporal_store(cr   + bg[0] * om, out_rgb + (size_t)ray*3 + 0);
        __builtin_nontemporal_store(cgrn + bg[1] * om, out_rgb + (size_t)ray*3 + 1);
        __builtin_nontemporal_store(cb   + bg[2] * om, out_rgb + (size_t)ray*3 + 2);
        __builtin_nontemporal_store(acc, out_acc + ray);
    }
}

extern "C" void kernel_launch(void* const* d_in, const int* in_sizes, int n_in,
                              void* d_out, int out_size, void* d_ws, size_t ws_size,
                              hipStream_t stream) {
    const float* ray_samples = (const float*)d_in[0];
    const float* densities   = (const float*)d_in[1];
    const float* rgb         = (const float*)d_in[2];
    const float* bg          = (const float*)d_in[3];

    float* o = (float*)d_out;
    float* out_rgb = o;                                    // N*3
    float* out_acc = o + (size_t)NRAYS * 3;                // N
    float* out_w   = o + (size_t)NRAYS * 3 + NRAYS;        // N*S

    dim3 grid(NRAYS / 4), block(256);
    hipLaunchKernelGGL(nerf_render_kernel, grid, block, 0, stream,
                       ray_samples, densities, rgb, bg, out_rgb, out_acc, out_w);
}

// Round 6
// 147.491 us; speedup vs baseline: 1.1537x; 1.0118x over previous
//
#include <hip/hip_runtime.h>

constexpr int NRAYS = 131072;
constexpr float DELTA_INF_F = 1e10f;
constexpr float EPS_F = 1e-10f;

typedef float floatx4 __attribute__((ext_vector_type(4)));

// One 64-lane wave per ray; 48 active lanes, lane l owns samples 4l..4l+3.
// Everything lane-local: no LDS, no barriers. Pure float4 traffic.
__global__ __launch_bounds__(256) void nerf_render_kernel(
    const float4* __restrict__ rsF4,    // [N*144] positions
    const float4* __restrict__ denF4,   // [N*48]  densities
    const float4* __restrict__ rgbF4,   // [N*144] rgb
    const float* __restrict__ bg,       // [3]
    float* __restrict__ out_rgb,        // [N,3]
    float* __restrict__ out_acc,        // [N]
    float4* __restrict__ out_wF4)       // [N*48]
{
    const int lane = threadIdx.x & 63;
    const int ray  = (blockIdx.x << 2) + (threadIdx.x >> 6);
    const bool act = lane < 48;
    const float4 Z = make_float4(0.f, 0.f, 0.f, 0.f);

    float4 P0 = Z, P1 = Z, P2 = Z, D = Z, C0 = Z, C1 = Z, C2 = Z;
    if (act) {
        const float4* rp = rsF4 + (size_t)ray * 144 + 3 * lane;
        P0 = rp[0]; P1 = rp[1]; P2 = rp[2];
        D = denF4[(size_t)ray * 48 + lane];
        const float4* rc = rgbF4 + (size_t)ray * 144 + 3 * lane;
        C0 = rc[0]; C1 = rc[1]; C2 = rc[2];
    }

    // ---- unpack 4 samples ----
    float x0 = P0.x, y0 = P0.y, z0 = P0.z;
    float x1 = P0.w, y1 = P1.x, z1 = P1.y;
    float x2 = P1.z, y2 = P1.w, z2 = P2.x;
    float x3 = P2.y, y3 = P2.z, z3 = P2.w;

    float nx = __shfl_down(x0, 1);
    float ny = __shfl_down(y0, 1);
    float nz = __shfl_down(z0, 1);

    float dx = x1 - x0, dy = y1 - y0, dz = z1 - z0;
    float d0 = sqrtf(dx * dx + dy * dy + dz * dz);
    dx = x2 - x1; dy = y2 - y1; dz = z2 - z1;
    float d1 = sqrtf(dx * dx + dy * dy + dz * dz);
    dx = x3 - x2; dy = y3 - y2; dz = z3 - z2;
    float d2 = sqrtf(dx * dx + dy * dy + dz * dz);
    dx = nx - x3; dy = ny - y3; dz = nz - z3;
    float d3 = (lane == 47) ? DELTA_INF_F : sqrtf(dx * dx + dy * dy + dz * dz);

    // ---- alpha / transmittance (mirror reference algebra) ----
    float e0 = __expf(-fmaxf(D.x, 0.f) * d0);
    float e1 = __expf(-fmaxf(D.y, 0.f) * d1);
    float e2 = __expf(-fmaxf(D.z, 0.f) * d2);
    float e3 = __expf(-fmaxf(D.w, 0.f) * d3);
    float a0 = 1.f - e0, a1 = 1.f - e1, a2 = 1.f - e2, a3 = 1.f - e3;
    float t0 = (1.f - a0) + EPS_F;
    float t1 = (1.f - a1) + EPS_F;
    float t2 = (1.f - a2) + EPS_F;
    float t3 = (1.f - a3) + EPS_F;

    // ---- exclusive cumprod across lanes ----
    float t01 = t0 * t1;
    float t012 = t01 * t2;
    float incl = t012 * t3;
#pragma unroll
    for (int off = 1; off < 64; off <<= 1) {
        float t = __shfl_up(incl, off);
        if (lane >= off) incl *= t;
    }
    float pref = __shfl_up(incl, 1);
    if (lane == 0) pref = 1.f;

    float w0 = a0 * pref;
    float w1 = a1 * pref * t0;
    float w2 = a2 * pref * t01;
    float w3 = a3 * pref * t012;
    float acc = w0 + w1 + w2 + w3;

    // ---- coalesced NT weight store (one float4 per active lane) ----
    if (act) {
        floatx4 wv = {w0, w1, w2, w3};
        __builtin_nontemporal_store(wv,
            (floatx4*)(out_wF4 + (size_t)ray * 48 + lane));
    }

    // ---- weighted rgb, all lane-local ----
    float cr = w0 * C0.x + w1 * C0.w + w2 * C1.z + w3 * C2.y;
    float cg = w0 * C0.y + w1 * C1.x + w2 * C1.w + w3 * C2.z;
    float cb = w0 * C0.z + w1 * C1.y + w2 * C2.x + w3 * C2.w;

#pragma unroll
    for (int off = 32; off >= 1; off >>= 1) {
        cr  += __shfl_xor(cr, off);
        cg  += __shfl_xor(cg, off);
        cb  += __shfl_xor(cb, off);
        acc += __shfl_xor(acc, off);
    }

    if (lane == 0) {
        float om = 1.f - acc;
        __builtin_nontemporal_store(cr + bg[0] * om, out_rgb + (size_t)ray * 3 + 0);
        __builtin_nontemporal_store(cg + bg[1] * om, out_rgb + (size_t)ray * 3 + 1);
        __builtin_nontemporal_store(cb + bg[2] * om, out_rgb + (size_t)ray * 3 + 2);
        __builtin_nontemporal_store(acc, out_acc + ray);
    }
}

extern "C" void kernel_launch(void* const* d_in, const int* in_sizes, int n_in,
                              void* d_out, int out_size, void* d_ws, size_t ws_size,
                              hipStream_t stream) {
    const float4* rsF4  = (const float4*)d_in[0];
    const float4* denF4 = (const float4*)d_in[1];
    const float4* rgbF4 = (const float4*)d_in[2];
    const float*  bg    = (const float*)d_in[3];

    float* o = (float*)d_out;
    float*  out_rgb = o;                                  // N*3
    float*  out_acc = o + (size_t)NRAYS * 3;              // N
    float4* out_wF4 = (float4*)(o + (size_t)NRAYS * 4);   // N*192

    dim3 grid(NRAYS / 4), block(256);
    hipLaunchKernelGGL(nerf_render_kernel, grid, block, 0, stream,
                       rsF4, denF4, rgbF4, bg, out_rgb, out_acc, out_wF4);
}